// Round 2
// baseline (1388.272 us; speedup 1.0000x reference)
//
#include <hip/hip_runtime.h>
#include <stdint.h>

typedef short bf16x8 __attribute__((ext_vector_type(8)));
typedef float f32x4 __attribute__((ext_vector_type(4)));
typedef unsigned int u32x2 __attribute__((ext_vector_type(2)));
typedef unsigned int u32x4 __attribute__((ext_vector_type(4)));

#define NBATCH 16
#define SEQ    2048
#define DD     1024
#define BM     32     // a-rows per workgroup (output rows)
#define KVB    32     // q-rows (softmax/contraction axis) per inner block
#define NWAVE  8
#define DCH    128    // d-chunk per wave
#define NKB    (SEQ / KVB)
#define VSTR   18     // u32 words per d-row of vT (pad 16->18: bank-conflict-free writes)

union Frag {
  uint32_t u[4];
  u32x4 u4;
  bf16x8 v;
};

__device__ __forceinline__ uint32_t rn16(uint32_t b) {
  // round-to-nearest bf16 (half-up), result as f32 bit pattern with low 16 = 0
  return (b + 0x8000u) & 0xffff0000u;
}
__device__ __forceinline__ uint32_t pack_rn(float x0, float x1) {
  // 2 x f32 -> packed bf16 pair (x0 low, x1 high), round-to-nearest
  return rn16(__float_as_uint(x1)) | (rn16(__float_as_uint(x0)) >> 16);
}

__device__ __forceinline__ void cvt_hl(const float* x, Frag& fh, Frag& fl) {
#pragma unroll
  for (int i = 0; i < 4; ++i) {
    float x0 = x[2 * i], x1 = x[2 * i + 1];
    uint32_t h0 = rn16(__float_as_uint(x0));
    uint32_t h1 = rn16(__float_as_uint(x1));
    fh.u[i] = h1 | (h0 >> 16);
    // x - hi is exact in f32; lo absorbs the bf16 rounding error
    fl.u[i] = pack_rn(x0 - __uint_as_float(h0), x1 - __uint_as_float(h1));
  }
}

__device__ __forceinline__ f32x4 z4() {
  f32x4 v; v[0] = 0.f; v[1] = 0.f; v[2] = 0.f; v[3] = 0.f; return v;
}

__global__ __launch_bounds__(512, 2)
void attn_fused(const float* __restrict__ Qg, const float* __restrict__ Ag,
                float* __restrict__ Og) {
  // LDS ~114 KB -> 1 block/CU, 8 waves
  __shared__ uint32_t vT[NWAVE][128 * VSTR];   // V tile, d-major: word [d][kv&15] = (Q[kv+16]<<16)|Q[kv]
  __shared__ float sp[NWAVE][BM][36];          // per-wave partial S^T
  __shared__ float ssum[BM][36];               // reduced S^T

  const int tid  = threadIdx.x;
  const int w    = tid >> 6;
  const int lane = tid & 63;
  const int g    = lane >> 4;
  const int m    = lane & 15;

  const int bid  = (int)blockIdx.x;
  const int b    = bid >> 6;        // SEQ/BM = 64 blocks per batch
  const int ablk = bid & 63;
  const int dw   = w * DCH;

  const float* Qb    = Qg + (size_t)b * SEQ * DD;
  const float* Abase = Ag + ((size_t)b * SEQ + ablk * BM) * DD;
  float*       Ob    = Og + ((size_t)b * SEQ + ablk * BM) * DD;

  // ---- a-block fragments (B-operand of S^T): [rt][kt], hi+lo, resident in regs
  Frag ah[2][4], al[2][4];
#pragma unroll
  for (int rt = 0; rt < 2; ++rt) {
#pragma unroll
    for (int kt = 0; kt < 4; ++kt) {
      const float* src = Abase + (size_t)(rt * 16 + m) * DD + dw + kt * 32 + g * 8;
      f32x4 v0 = ((const f32x4*)src)[0];
      f32x4 v1 = ((const f32x4*)src)[1];
      float x[8];
#pragma unroll
      for (int i = 0; i < 4; ++i) { x[i] = v0[i]; x[4 + i] = v1[i]; }
      cvt_hl(x, ah[rt][kt], al[rt][kt]);
    }
  }

  f32x4 oacc[2][8];
#pragma unroll
  for (int mt = 0; mt < 2; ++mt)
#pragma unroll
    for (int nt = 0; nt < 8; ++nt) oacc[mt][nt] = z4();

  float M0 = -1e30f, M1 = -1e30f, L0 = 0.f, L1 = 0.f;
  uint32_t* vTw = &vT[w][0];

#pragma unroll 1
  for (int kb = 0; kb < NKB; ++kb) {
    const int kv0 = kb * KVB;
    f32x4 st[2][2];
#pragma unroll
    for (int ct = 0; ct < 2; ++ct)
#pragma unroll
      for (int rt = 0; rt < 2; ++rt) st[ct][rt] = z4();

    // ---- S^T partial over this wave's d-chunk (3-term bf16 hi/lo)
#pragma unroll
    for (int kt = 0; kt < 4; ++kt) {
      Frag qh[2], ql[2];
#pragma unroll
      for (int kvt = 0; kvt < 2; ++kvt) {
        const float* src = Qb + (size_t)(kv0 + kvt * 16 + m) * DD + dw + kt * 32 + g * 8;
        f32x4 v0 = ((const f32x4*)src)[0];
        f32x4 v1 = ((const f32x4*)src)[1];
        float x[8];
#pragma unroll
        for (int i = 0; i < 4; ++i) { x[i] = v0[i]; x[4 + i] = v1[i]; }
        cvt_hl(x, qh[kvt], ql[kvt]);
      }
      // stage V (hi parts) d-major: word [d][m] = (Q[16+m]<<16) | Q[m]
      const int dbase = kt * 32 + g * 8;
#pragma unroll
      for (int i = 0; i < 4; ++i) {
        uint32_t we = (qh[1].u[i] << 16) | (qh[0].u[i] & 0xffffu);   // d = dbase+2i
        uint32_t wo = (qh[1].u[i] & 0xffff0000u) | (qh[0].u[i] >> 16); // d = dbase+2i+1
        vTw[(dbase + 2 * i) * VSTR + m]     = we;
        vTw[(dbase + 2 * i + 1) * VSTR + m] = wo;
      }
#pragma unroll
      for (int ct = 0; ct < 2; ++ct)
#pragma unroll
        for (int rt = 0; rt < 2; ++rt) {
          st[ct][rt] = __builtin_amdgcn_mfma_f32_16x16x32_bf16(qh[ct].v, ah[rt][kt].v, st[ct][rt], 0, 0, 0);
          st[ct][rt] = __builtin_amdgcn_mfma_f32_16x16x32_bf16(qh[ct].v, al[rt][kt].v, st[ct][rt], 0, 0, 0);
          st[ct][rt] = __builtin_amdgcn_mfma_f32_16x16x32_bf16(ql[ct].v, ah[rt][kt].v, st[ct][rt], 0, 0, 0);
        }
    }

    // ---- stage A: write per-wave partials
#pragma unroll
    for (int ct = 0; ct < 2; ++ct)
#pragma unroll
      for (int rt = 0; rt < 2; ++rt)
        *(f32x4*)&sp[w][rt * 16 + m][ct * 16 + g * 4] = st[ct][rt];
    __syncthreads();

    // ---- stage B: cross-wave reduce (512 threads x 2 positions)
#pragma unroll
    for (int rep = 0; rep < 2; ++rep) {
      const int p = tid + rep * 512;
      const int r = p >> 5, c = p & 31;
      float acc = 0.f;
#pragma unroll
      for (int ww = 0; ww < NWAVE; ++ww) acc += sp[ww][r][c];
      ssum[r][c] = acc;
    }
    __syncthreads();

    // ---- stage C: full S^T in C-fragment layout; online softmax (redundant per wave)
    f32x4 sv[2][2];
#pragma unroll
    for (int ct = 0; ct < 2; ++ct)
#pragma unroll
      for (int rt = 0; rt < 2; ++rt)
        sv[ct][rt] = *(const f32x4*)&ssum[rt * 16 + m][ct * 16 + g * 4];

    float mx0 = -1e30f, mx1 = -1e30f;
#pragma unroll
    for (int ct = 0; ct < 2; ++ct)
#pragma unroll
      for (int j = 0; j < 4; ++j) {
        mx0 = fmaxf(mx0, sv[ct][0][j]);
        mx1 = fmaxf(mx1, sv[ct][1][j]);
      }
    mx0 = fmaxf(mx0, __shfl_xor(mx0, 16));
    mx0 = fmaxf(mx0, __shfl_xor(mx0, 32));
    mx1 = fmaxf(mx1, __shfl_xor(mx1, 16));
    mx1 = fmaxf(mx1, __shfl_xor(mx1, 32));

    if (__any((mx0 > M0) | (mx1 > M1))) {
      const float nM0 = fmaxf(M0, mx0), nM1 = fmaxf(M1, mx1);
      const float c0 = __expf(M0 - nM0), c1 = __expf(M1 - nM1);
      M0 = nM0; M1 = nM1;
      L0 *= c0; L1 *= c1;
      // factor for output row g*4+j lives on lane (g*4+j) of the low 16
      f32x4 cr0, cr1;
#pragma unroll
      for (int j = 0; j < 4; ++j) {
        cr0[j] = __shfl(c0, g * 4 + j);
        cr1[j] = __shfl(c1, g * 4 + j);
      }
#pragma unroll
      for (int nt = 0; nt < 8; ++nt)
#pragma unroll
        for (int j = 0; j < 4; ++j) {
          oacc[0][nt][j] *= cr0[j];
          oacc[1][nt][j] *= cr1[j];
        }
    }

    // P in registers, interleaved kv-labeling matching vT words:
    //  pa elem (2*jj+ct) <-> kv = ct*16 + g*4 + jj  (same label as V-frag elem)
    f32x4 p00, p10, p01, p11;   // [ct][row-half]
#pragma unroll
    for (int j = 0; j < 4; ++j) {
      p00[j] = __expf(sv[0][0][j] - M0);
      p10[j] = __expf(sv[1][0][j] - M0);
      p01[j] = __expf(sv[0][1][j] - M1);
      p11[j] = __expf(sv[1][1][j] - M1);
    }
    float rs0 = 0.f, rs1 = 0.f;
#pragma unroll
    for (int j = 0; j < 4; ++j) {
      rs0 += p00[j] + p10[j];
      rs1 += p01[j] + p11[j];
    }
    rs0 += __shfl_xor(rs0, 16); rs0 += __shfl_xor(rs0, 32);
    rs1 += __shfl_xor(rs1, 16); rs1 += __shfl_xor(rs1, 32);
    L0 += rs0; L1 += rs1;

    Frag pa0, pa1;
#pragma unroll
    for (int j = 0; j < 4; ++j) {
      pa0.u[j] = pack_rn(p00[j], p10[j]);
      pa1.u[j] = pack_rn(p01[j], p11[j]);
    }

    // ---- PV: A = P (regs), B = V from vT (plain u32x2 loads; labels match)
#pragma unroll
    for (int nt = 0; nt < 8; ++nt) {
      const uint32_t* src = &vTw[(nt * 16 + m) * VSTR + g * 4];
      Frag bq;
      *(u32x2*)&bq.u[0] = *(const u32x2*)&src[0];
      *(u32x2*)&bq.u[2] = *(const u32x2*)&src[2];
      oacc[0][nt] = __builtin_amdgcn_mfma_f32_16x16x32_bf16(pa0.v, bq.v, oacc[0][nt], 0, 0, 0);
      oacc[1][nt] = __builtin_amdgcn_mfma_f32_16x16x32_bf16(pa1.v, bq.v, oacc[1][nt], 0, 0, 0);
    }
  }

  // ---- epilogue: normalize by L and store
  f32x4 i0, i1;
#pragma unroll
  for (int j = 0; j < 4; ++j) {
    i0[j] = 1.f / __shfl(L0, g * 4 + j);
    i1[j] = 1.f / __shfl(L1, g * 4 + j);
  }
#pragma unroll
  for (int mt = 0; mt < 2; ++mt)
#pragma unroll
    for (int nt = 0; nt < 8; ++nt)
#pragma unroll
      for (int j = 0; j < 4; ++j) {
        const int r  = mt * 16 + g * 4 + j;
        const int dc = dw + nt * 16 + m;
        Ob[(size_t)r * DD + dc] = oacc[mt][nt][j] * (mt ? i1[j] : i0[j]);
      }
}

extern "C" void kernel_launch(void* const* d_in, const int* in_sizes, int n_in,
                              void* d_out, int out_size, void* d_ws, size_t ws_size,
                              hipStream_t stream) {
  const float* q = (const float*)d_in[0];
  const float* a = (const float*)d_in[1];
  float* o = (float*)d_out;
  dim3 grid(NBATCH * (SEQ / BM));   // 1024 workgroups
  dim3 block(512);                  // 8 waves
  attn_fused<<<grid, block, 0, stream>>>(q, a, o);
  (void)in_sizes; (void)n_in; (void)out_size; (void)d_ws; (void)ws_size;
}